// Round 4
// baseline (72.219 us; speedup 1.0000x reference)
//
#include <hip/hip_runtime.h>

#define HH 512
#define WW 512

__device__ __forceinline__ float fexp2(float x) { return __builtin_amdgcn_exp2f(x); }
__device__ __forceinline__ float flog2(float x) { return __builtin_amdgcn_logf(x); }

struct Node { float o0, o1, o2, s0, s1, s2; };

// L layout: 6 planes of [18 rows][40 cols]; plane p at p*720. col k maps to
// global w = w0 - 4 + k; row r maps to global h = h0 + r. Valid data k=3..37.
__device__ __forceinline__ Node nd(const float* Lp, int r, int k) {
    const int i = r * 40 + k;
    Node n;
    n.o0 = Lp[i];          n.o1 = Lp[i + 720];  n.o2 = Lp[i + 1440];
    n.s0 = Lp[i + 2160];   n.s1 = Lp[i + 2880]; n.s2 = Lp[i + 3600];
    return n;
}

// one unordered pair (i,j): small term (cf*(1-mi)+cb*(1-mj))*wr*sum(t^0.8)
//                         + large term (cf*mi+cb*mj)*wsd*sum(t^2)
__device__ __forceinline__ float pairf(const Node& I, const Node& J,
    float mi, float mj, float cf, float cb, float wsd)
{
    float d0 = I.o0 - J.o0, d1 = I.o1 - J.o1, d2 = I.o2 - J.o2;
    float sO = fmaf(d0, d0, fmaf(d1, d1, d2 * d2));
    float e0 = I.s0 - J.s0, e1 = I.s1 - J.s1, e2 = I.s2 - J.s2;
    float t0 = fabsf(e0) + 1e-8f;
    float t1 = fabsf(e1) + 1e-8f;
    float t2 = fabsf(e2) + 1e-8f;
    float ps = fexp2(0.8f * flog2(t0)) + fexp2(0.8f * flog2(t1)) + fexp2(0.8f * flog2(t2));
    float wr = fexp2(-0.72134752044448169f * sO);   // exp(-0.5*sO)
    float wsm = fmaf(cf, -mi, cf) + fmaf(cb, -mj, cb);
    float wl  = fmaf(cf, mi, cb * mj);
    float sq  = fmaf(t0, t0, fmaf(t1, t1, t2 * t2));
    return fmaf(wsm * wr, ps, wl * wsd * sq);
}

// all 4 owned pairs + center term for pixel at (h,w) global
__device__ __forceinline__ float pixel(const float* Lp,
    const Node& C, const Node& E, const Node& S, const Node& SE, const Node& SW,
    float mi, float mE, float mS, float mSE, float mSW, int h, int w)
{
    float aE = (w == 0)   ? 2.f : 1.f, bE = (w == 510) ? 2.f : 1.f;
    float aS = (h == 0)   ? 2.f : 1.f, bS = (h == 510) ? 2.f : 1.f;
    float aW = (w == 511) ? 2.f : 1.f, bW = (w == 1)   ? 2.f : 1.f;
    bool  vE = (w <= 510), vS = (h <= 510);
    bool  vD = vS && vE,   vW = vS && (w >= 1);
    float cEf = vE ? aE : 0.f,      cEb = vE ? bE : 0.f;
    float cSf = vS ? aS : 0.f,      cSb = vS ? bS : 0.f;
    float cDf = vD ? aS * aE : 0.f, cDb = vD ? bS * bE : 0.f;
    float cWf = vW ? aS * aW : 0.f, cWb = vW ? bS * bW : 0.f;

    // center offset: small: 3*(1e-8)^0.8, large: 3e-16
    float a = fmaf(mi, 3e-16f - 1.1943215e-6f, 1.1943215e-6f);
    a += pairf(C, E,  mi, mE,  cEf, cEb, 0.60653065971263342f);
    a += pairf(C, S,  mi, mS,  cSf, cSb, 0.60653065971263342f);
    a += pairf(C, SE, mi, mSE, cDf, cDb, 0.36787944117144233f);
    a += pairf(C, SW, mi, mSW, cWf, cWb, 0.36787944117144233f);
    return a;
}

__global__ __launch_bounds__(256) void smooth_loss_kernel(
    const float* __restrict__ orig, const float* __restrict__ smo,
    float* __restrict__ out)
{
    __shared__ float L[4320];     // 6 * 18 * 40
    __shared__ float M[578];      // mask plane: 17 rows x 34 cols (c=0 <-> w0-1)
    __shared__ float wsum[4];

    const int bid  = blockIdx.x;        // 8 imgs * 32 trow * 16 tcol
    const int b    = bid >> 9;
    const int t    = bid & 511;
    const int trow = t >> 4;
    const int tcol = t & 15;
    const int h0 = trow << 4;           // 16-row tile
    const int w0 = tcol << 5;           // 32-col tile

    // ---- bulk staging: 1080 float4 jobs via global_load_lds width 16 ----
    for (int it = 0; it < 5; ++it) {
        const int j = it * 256 + (int)threadIdx.x;
        const int p   = j / 180;
        const int rem = j - p * 180;
        const int r   = rem / 10;
        const int q   = rem - r * 10;
        int gh = h0 + r; gh = gh > 511 ? 1022 - gh : gh;
        int wb = w0 - 4 + (q << 2);
        wb = wb < 0 ? 0 : (wb > 508 ? 508 : wb);   // clamp (garbage fixed below)
        const float* base = (p < 3) ? orig : smo;
        const int ch = (p < 3) ? p : p - 3;
        const float* gp = base + ((b * 3 + ch) << 18) + (gh << 9) + wb;
        if (j < 1080)
            __builtin_amdgcn_global_load_lds(
                (const __attribute__((address_space(1))) unsigned int*)gp,
                (__attribute__((address_space(3))) unsigned int*)&L[(it * 256 + ((int)threadIdx.x & ~63)) * 4],
                16, 0, 0);
    }
    __syncthreads();

    // ---- scalar fix-ups for reflected halo columns (edge-column tiles) ----
    if (tcol == 0) {
        for (int j2 = threadIdx.x; j2 < 108; j2 += 256) {   // k=3 <-> w=-1 -> 1
            const int p = j2 / 18, r = j2 - p * 18;
            int gh = h0 + r; gh = gh > 511 ? 1022 - gh : gh;
            const float* base = (p < 3) ? orig : smo;
            const int ch = (p < 3) ? p : p - 3;
            L[p * 720 + r * 40 + 3] = base[((b * 3 + ch) << 18) + (gh << 9) + 1];
        }
    } else if (tcol == 15) {
        for (int j2 = threadIdx.x; j2 < 216; j2 += 256) {   // k=36,37 <-> w=512,513 -> 510,509
            const int kk = j2 & 1;
            const int pr = j2 >> 1;
            const int p = pr / 18, r = pr - p * 18;
            int gh = h0 + r; gh = gh > 511 ? 1022 - gh : gh;
            const float* base = (p < 3) ? orig : smo;
            const int ch = (p < 3) ? p : p - 3;
            L[p * 720 + r * 40 + 36 + kk] = base[((b * 3 + ch) << 18) + (gh << 9) + (510 - kk)];
        }
    }
    __syncthreads();

    // ---- pass 1: mask plane. m(r,cm), cm=0..33 <-> w0-1+cm, r=0..16 ----
    for (int e = threadIdx.x; e < 578; e += 256) {
        const int r = e / 34, cm = e - r * 34;
        const int vb = r * 40 + cm + 3;
        float eo = 0.f, es = 0.f;
        #pragma unroll
        for (int p = 0; p < 3; ++p) {
            float c0 = L[p * 720 + vb], r0 = L[p * 720 + vb + 1], s0 = L[p * 720 + vb + 40];
            float d1 = c0 - s0, d2 = c0 - r0;
            eo += d1 * d1 + d2 * d2;
            float c1 = L[(p + 3) * 720 + vb], r1 = L[(p + 3) * 720 + vb + 1], s1 = L[(p + 3) * 720 + vb + 40];
            float f1 = c1 - s1, f2 = c1 - r1;
            es += f1 * f1 + f2 * f2;
        }
        M[e] = (eo < 1.f && (es - eo) > 1.f) ? 1.f : 0.f;
    }
    __syncthreads();

    // ---- pass 2: 2 pixels per thread (rows 2g, 2g+1; col tx) ----
    const int tx  = threadIdx.x & 31;
    const int g   = threadIdx.x >> 5;
    const int pr0 = g << 1;
    const int k   = tx + 4;             // center col in L-k space

    float acc = 0.f;
    {
        Node A  = nd(L, pr0,     k);
        Node AE = nd(L, pr0,     k + 1);
        Node B  = nd(L, pr0 + 1, k);
        Node BE = nd(L, pr0 + 1, k + 1);
        Node BW = nd(L, pr0 + 1, k - 1);
        float mA  = M[pr0 * 34 + tx + 1],       mAE = M[pr0 * 34 + tx + 2];
        float mB  = M[(pr0 + 1) * 34 + tx + 1], mBE = M[(pr0 + 1) * 34 + tx + 2];
        float mBW = M[(pr0 + 1) * 34 + tx];
        acc += pixel(L, A, AE, B, BE, BW, mA, mAE, mB, mBE, mBW, h0 + pr0, w0 + tx);

        Node C  = nd(L, pr0 + 2, k);
        Node CE = nd(L, pr0 + 2, k + 1);
        Node CW = nd(L, pr0 + 2, k - 1);
        float mC  = M[(pr0 + 2) * 34 + tx + 1], mCE = M[(pr0 + 2) * 34 + tx + 2];
        float mCW = M[(pr0 + 2) * 34 + tx];
        acc += pixel(L, B, BE, C, CE, CW, mB, mBE, mC, mCE, mCW, h0 + pr0 + 1, w0 + tx);
    }

    acc *= (1.0f / 56623104.0f);        // mean over 8*9*3*512*512

    #pragma unroll
    for (int o = 32; o > 0; o >>= 1)
        acc += __shfl_down(acc, o, 64);

    const int lane = threadIdx.x & 63;
    const int wid  = threadIdx.x >> 6;
    if (lane == 0) wsum[wid] = acc;
    __syncthreads();
    if (threadIdx.x == 0)
        atomicAdd(out, wsum[0] + wsum[1] + wsum[2] + wsum[3]);
}

extern "C" void kernel_launch(void* const* d_in, const int* in_sizes, int n_in,
                              void* d_out, int out_size, void* d_ws, size_t ws_size,
                              hipStream_t stream) {
    const float* orig = (const float*)d_in[0];
    const float* smo  = (const float*)d_in[1];
    float* out = (float*)d_out;

    (void)hipMemsetAsync(out, 0, sizeof(float), stream);
    smooth_loss_kernel<<<4096, 256, 0, stream>>>(orig, smo, out);
}

// Round 5
// 46.719 us; speedup vs baseline: 1.5458x; 1.5458x over previous
//
#include <hip/hip_runtime.h>

#define HH 512
#define WW 512
#define LSTRIDE 72
#define LPLANE 1296        // 18 rows * 72 cols
#define MSTRIDE 67

__device__ __forceinline__ float fexp2(float x) { return __builtin_amdgcn_exp2f(x); }
__device__ __forceinline__ float flog2(float x) { return __builtin_amdgcn_logf(x); }

struct Node { float o0, o1, o2, s0, s1, s2; };

// L col k <-> global w = w0 - 4 + k ; row r <-> global h = h0 + r
__device__ __forceinline__ Node nd(const float* L, int r, int k) {
    const int i = r * LSTRIDE + k;
    Node n;
    n.o0 = L[i];              n.o1 = L[i + LPLANE];     n.o2 = L[i + 2 * LPLANE];
    n.s0 = L[i + 3 * LPLANE]; n.s1 = L[i + 4 * LPLANE]; n.s2 = L[i + 5 * LPLANE];
    return n;
}

// unordered pair (i,j): (cf*(1-mi)+cb*(1-mj))*wr*sum(t^0.8) + (cf*mi+cb*mj)*wsd*sum(t^2)
__device__ __forceinline__ float pairf(const Node& I, const Node& J,
    float mi, float mj, float cf, float cb, float wsd)
{
    float d0 = I.o0 - J.o0, d1 = I.o1 - J.o1, d2 = I.o2 - J.o2;
    float sO = fmaf(d0, d0, fmaf(d1, d1, d2 * d2));
    float t0 = fabsf(I.s0 - J.s0) + 1e-8f;
    float t1 = fabsf(I.s1 - J.s1) + 1e-8f;
    float t2 = fabsf(I.s2 - J.s2) + 1e-8f;
    float ps = fexp2(0.8f * flog2(t0)) + fexp2(0.8f * flog2(t1)) + fexp2(0.8f * flog2(t2));
    float wr = fexp2(-0.72134752044448169f * sO);
    float wsm = fmaf(cf, -mi, cf) + fmaf(cb, -mj, cb);
    float wl  = fmaf(cf, mi, cb * mj);
    float sq  = fmaf(t0, t0, fmaf(t1, t1, t2 * t2));
    return fmaf(wsm * wr, ps, wl * wsd * sq);
}

// 4 owned pairs + center term for global pixel (h,w)
__device__ __forceinline__ float pixel(
    const Node& C, const Node& E, const Node& S, const Node& SE, const Node& SW,
    float mi, float mE, float mS, float mSE, float mSW, int h, int w)
{
    float aE = (w == 0)   ? 2.f : 1.f, bE = (w == 510) ? 2.f : 1.f;
    float aS = (h == 0)   ? 2.f : 1.f, bS = (h == 510) ? 2.f : 1.f;
    float aW = (w == 511) ? 2.f : 1.f, bW = (w == 1)   ? 2.f : 1.f;
    bool  vE = (w <= 510), vS = (h <= 510);
    bool  vD = vS && vE,   vW = vS && (w >= 1);
    float cEf = vE ? aE : 0.f,      cEb = vE ? bE : 0.f;
    float cSf = vS ? aS : 0.f,      cSb = vS ? bS : 0.f;
    float cDf = vD ? aS * aE : 0.f, cDb = vD ? bS * bE : 0.f;
    float cWf = vW ? aS * aW : 0.f, cWb = vW ? bS * bW : 0.f;

    float a = fmaf(mi, 3e-16f - 1.1943215e-6f, 1.1943215e-6f);  // center offset
    a += pairf(C, E,  mi, mE,  cEf, cEb, 0.60653065971263342f);
    a += pairf(C, S,  mi, mS,  cSf, cSb, 0.60653065971263342f);
    a += pairf(C, SE, mi, mSE, cDf, cDb, 0.36787944117144233f);
    a += pairf(C, SW, mi, mSW, cWf, cWb, 0.36787944117144233f);
    return a;
}

__global__ __launch_bounds__(256, 4) void smooth_loss_kernel(
    const float* __restrict__ orig, const float* __restrict__ smo,
    float* __restrict__ out)
{
    __shared__ float L[6 * LPLANE];     // 7776 floats
    __shared__ float M[17 * MSTRIDE];   // mask plane, cols cm=0..65 <-> w0-1+cm
    __shared__ float wsum[4];

    const int bid  = blockIdx.x;        // 8 imgs * 32 trow * 8 tcol
    const int b    = bid >> 8;
    const int t    = bid & 255;
    const int trow = t >> 3;
    const int tcol = t & 7;
    const int h0 = trow << 4;           // 16-row tile
    const int w0 = tcol << 6;           // 64-col tile
    const int tid = threadIdx.x;

    // ---- bulk staging: 1944 float4 jobs (6 planes x 18 rows x 18 chunks) ----
    for (int it = 0; it < 8; ++it) {
        const int j = it * 256 + tid;
        const int p   = j / 324;
        const int rem = j - p * 324;
        const int r   = rem / 18;
        const int q   = rem - r * 18;
        int gh = h0 + r; gh = gh > 511 ? 1022 - gh : gh;
        int wb = w0 - 4 + (q << 2);
        wb = wb < 0 ? 0 : (wb > 508 ? 508 : wb);   // clamped garbage fixed below
        const float* base = (p < 3) ? orig : smo;
        const int ch = (p < 3) ? p : p - 3;
        const float* gp = base + ((b * 3 + ch) << 18) + (gh << 9) + wb;
        if (j < 1944)
            __builtin_amdgcn_global_load_lds(
                (const __attribute__((address_space(1))) unsigned int*)gp,
                (__attribute__((address_space(3))) unsigned int*)&L[(it * 256 + (tid & ~63)) * 4],
                16, 0, 0);
    }
    __syncthreads();

    // ---- fix-ups for reflected halo columns (block-uniform condition) ----
    if (tcol == 0) {
        for (int j2 = tid; j2 < 108; j2 += 256) {          // k=3 <-> w=-1 -> 1
            const int p = j2 / 18, r = j2 - p * 18;
            int gh = h0 + r; gh = gh > 511 ? 1022 - gh : gh;
            const float* base = (p < 3) ? orig : smo;
            const int ch = (p < 3) ? p : p - 3;
            L[p * LPLANE + r * LSTRIDE + 3] = base[((b * 3 + ch) << 18) + (gh << 9) + 1];
        }
        __syncthreads();
    } else if (tcol == 7) {
        for (int j2 = tid; j2 < 324; j2 += 256) {          // k=68+kk <-> w=512+kk -> 510-kk
            const int kk = j2 % 3;
            const int pr = j2 / 3;
            const int p = pr / 18, r = pr - p * 18;
            int gh = h0 + r; gh = gh > 511 ? 1022 - gh : gh;
            const float* base = (p < 3) ? orig : smo;
            const int ch = (p < 3) ? p : p - 3;
            L[p * LPLANE + r * LSTRIDE + 68 + kk] = base[((b * 3 + ch) << 18) + (gh << 9) + (510 - kk)];
        }
        __syncthreads();
    }

    // ---- pass 1: mask plane (17 rows x 66 cols) ----
    for (int e = tid; e < 1122; e += 256) {
        const int r = e / 66, cm = e - r * 66;
        const int vb = r * LSTRIDE + cm + 3;
        float eo = 0.f, es = 0.f;
        #pragma unroll
        for (int p = 0; p < 3; ++p) {
            float c0 = L[p * LPLANE + vb];
            float d1 = c0 - L[p * LPLANE + vb + LSTRIDE];
            float d2 = c0 - L[p * LPLANE + vb + 1];
            eo += d1 * d1 + d2 * d2;
            float c1 = L[(p + 3) * LPLANE + vb];
            float f1 = c1 - L[(p + 3) * LPLANE + vb + LSTRIDE];
            float f2 = c1 - L[(p + 3) * LPLANE + vb + 1];
            es += f1 * f1 + f2 * f2;
        }
        M[r * MSTRIDE + cm] = (eo < 1.f && (es - eo) > 1.f) ? 1.f : 0.f;
    }
    __syncthreads();

    // ---- pass 2: 2x2 pixel quad per thread ----
    const int qr = tid >> 5;            // 0..7  -> pixel rows 2qr, 2qr+1
    const int qc = tid & 31;            // 0..31 -> pixel cols 2qc, 2qc+1
    const int r0 = qr << 1;
    const int c0 = qc << 1;
    const int kb = c0 + 3;              // k of col c0-1

    float acc = 0.f;
    {
        // phase A: node rows r0, r0+1 (cols c0-1 .. c0+2)
        Node A0 = nd(L, r0,     kb),     A1 = nd(L, r0,     kb + 1);
        Node A2 = nd(L, r0,     kb + 2), A3 = nd(L, r0,     kb + 3);
        Node B0 = nd(L, r0 + 1, kb),     B1 = nd(L, r0 + 1, kb + 1);
        Node B2 = nd(L, r0 + 1, kb + 2), B3 = nd(L, r0 + 1, kb + 3);
        const int mb = r0 * MSTRIDE + c0;     // M index of col c0-1, row r0
        float mA1 = M[mb + 1], mA2 = M[mb + 2], mA3 = M[mb + 3];
        float mB0 = M[mb + MSTRIDE], mB1 = M[mb + MSTRIDE + 1];
        float mB2 = M[mb + MSTRIDE + 2], mB3 = M[mb + MSTRIDE + 3];

        acc += pixel(A1, A2, B1, B2, B0, mA1, mA2, mB1, mB2, mB0, h0 + r0, w0 + c0);
        acc += pixel(A2, A3, B2, B3, B1, mA2, mA3, mB2, mB3, mB1, h0 + r0, w0 + c0 + 1);

        // phase B: node row r0+2
        Node C0 = nd(L, r0 + 2, kb),     C1 = nd(L, r0 + 2, kb + 1);
        Node C2 = nd(L, r0 + 2, kb + 2), C3 = nd(L, r0 + 2, kb + 3);
        float mC0 = M[mb + 2 * MSTRIDE],     mC1 = M[mb + 2 * MSTRIDE + 1];
        float mC2 = M[mb + 2 * MSTRIDE + 2], mC3 = M[mb + 2 * MSTRIDE + 3];

        acc += pixel(B1, B2, C1, C2, C0, mB1, mB2, mC1, mC2, mC0, h0 + r0 + 1, w0 + c0);
        acc += pixel(B2, B3, C2, C3, C1, mB2, mB3, mC2, mC3, mC1, h0 + r0 + 1, w0 + c0 + 1);
    }

    acc *= (1.0f / 56623104.0f);        // mean over 8*9*3*512*512

    #pragma unroll
    for (int o = 32; o > 0; o >>= 1)
        acc += __shfl_down(acc, o, 64);

    const int lane = tid & 63;
    const int wid  = tid >> 6;
    if (lane == 0) wsum[wid] = acc;
    __syncthreads();
    if (tid == 0)
        atomicAdd(out, wsum[0] + wsum[1] + wsum[2] + wsum[3]);
}

extern "C" void kernel_launch(void* const* d_in, const int* in_sizes, int n_in,
                              void* d_out, int out_size, void* d_ws, size_t ws_size,
                              hipStream_t stream) {
    const float* orig = (const float*)d_in[0];
    const float* smo  = (const float*)d_in[1];
    float* out = (float*)d_out;

    (void)hipMemsetAsync(out, 0, sizeof(float), stream);
    smooth_loss_kernel<<<2048, 256, 0, stream>>>(orig, smo, out);
}